// Round 4
// baseline (248.685 us; speedup 1.0000x reference)
//
#include <hip/hip_runtime.h>
#include <hip/hip_bf16.h>

typedef __attribute__((ext_vector_type(4))) float f32x4;
typedef __attribute__((ext_vector_type(8))) short bf16x8;
typedef __attribute__((ext_vector_type(4))) unsigned short u16x4;
typedef __attribute__((ext_vector_type(8))) unsigned short u16x8;

__device__ __forceinline__ unsigned short f2bf(float f) {
    unsigned int u = __builtin_bit_cast(unsigned int, f);
    u += 0x7fffu + ((u >> 16) & 1u);   // RNE; inputs finite
    return (unsigned short)(u >> 16);
}

// swizzle in ushort units: rows are 64 ushorts (128 B); XOR bits 3..5 with row&7
#define SWZ(i) ((i) ^ ((((i) >> 6) & 7) << 3))

// ---------------- transpose+convert: W^T into tiled+swizzled bf16 ----------
// dst tile = [n>>ltw][k>>6] of (2^ltw * 64) ushorts; within-tile idx
// SWZ((n & (tw-1))*64 + (k&63)). This is exactly the LDS image the GEMMs
// stage with global_load_lds (linear dest) + swizzled ds_read (rule #21).
__global__ void transpose_cvt(const float* __restrict__ src,
                              unsigned short* __restrict__ dst,
                              int rows, int cols, int ltw) {
    int idx = blockIdx.x * 256 + threadIdx.x;     // idx = n*rows + k
    int n = idx / rows;
    int k = idx - n * rows;
    unsigned short v = f2bf(src[(size_t)k * cols + n]);
    int tw = 1 << ltw;
    int tile = (n >> ltw) * (rows >> 6) + (k >> 6);
    dst[(size_t)tile * (tw * 64) + SWZ((n & (tw - 1)) * 64 + (k & 63))] = v;
}

// ---------------- small GEMM (K=512): BM=64, BN=128 -----------------------
// EPI 0: D = Tbt (256-wide tiled+swizzled bf16) = acc + epi  [T = input@W1+W2]
// EPI 1: D(f32) = acc + bias[col]  -> writes OUT directly    [out = x@W3 + b]
template<int EPI>
__global__ __launch_bounds__(512, 4)
void gemm_small(const float* __restrict__ A, long lda,
                const unsigned short* __restrict__ Bt,
                int K,
                const float* __restrict__ epi, long lde,
                const float* __restrict__ bias,
                void* __restrict__ Dptr, long ldd) {
    __shared__ unsigned short sA[2][64 * 64];
    __shared__ unsigned short sB[2][128 * 64];

    const int t = threadIdx.x;
    const int l = t & 63;
    const int w = t >> 6;
    const int wm = w >> 2;              // 0..1
    const int wn = w & 3;               // 0..3

    int mt, nt;
    {
        int lin = blockIdx.y * gridDim.x + blockIdx.x;   // gridDim.y % 8 == 0
        int xcd = lin & 7;
        int slot = lin >> 3;
        int ppx = gridDim.y >> 3;
        mt = xcd * ppx + slot / gridDim.x;
        nt = slot % gridDim.x;
    }
    const long m0 = (long)mt * 64;
    const long n0 = (long)nt * 128;
    const int KT = K >> 6;
    const unsigned short* Bblk = Bt + (size_t)nt * KT * 8192;

    f32x4 acc[2][2];
    #pragma unroll
    for (int m = 0; m < 2; ++m)
        #pragma unroll
        for (int n = 0; n < 2; ++n)
            acc[m][n] = {0.f, 0.f, 0.f, 0.f};

    f32x4 aX0, aX1, aY0, aY1;

    auto gll_B = [&](int kt, int buf) {
        const unsigned short* src = Bblk + (size_t)kt * 8192 + t * 8;
        #pragma unroll
        for (int r = 0; r < 2; ++r)
            __builtin_amdgcn_global_load_lds(
                (const __attribute__((address_space(1))) void*)(src + r * 4096),
                (__attribute__((address_space(3))) void*)&sB[buf][r * 4096 + w * 512],
                16, 0, 0);
    };

    auto load_A = [&](int kt, f32x4& a0, f32x4& a1) {
        const float* p0 = &A[(m0 + (t >> 4)) * lda + (long)kt * 64 + ((t & 15) << 2)];
        const float* p1 = p0 + 32 * lda;
        asm volatile("global_load_dwordx4 %0, %2, off\n\t"
                     "global_load_dwordx4 %1, %3, off"
                     : "=&v"(a0), "=&v"(a1)
                     : "v"(p0), "v"(p1)
                     : "memory");
    };

    auto write_A = [&](int buf, const f32x4& a0, const f32x4& a1) {
        int e0 = t * 4;
        u16x4 w0 = {f2bf(a0[0]), f2bf(a0[1]), f2bf(a0[2]), f2bf(a0[3])};
        *reinterpret_cast<u16x4*>(&sA[buf][SWZ(e0)]) = w0;
        int e1 = 2048 + t * 4;
        u16x4 w1 = {f2bf(a1[0]), f2bf(a1[1]), f2bf(a1[2]), f2bf(a1[3])};
        *reinterpret_cast<u16x4*>(&sA[buf][SWZ(e1)]) = w1;
    };

    auto compute = [&](int buf) {
        #pragma unroll
        for (int kk = 0; kk < 2; ++kk) {
            bf16x8 af[2], bfr[2];
            const int kb = kk * 32 + ((l >> 4) << 3);
            #pragma unroll
            for (int m = 0; m < 2; ++m) {
                int row = wm * 32 + m * 16 + (l & 15);
                af[m] = *reinterpret_cast<const bf16x8*>(&sA[buf][SWZ(row * 64 + kb)]);
            }
            #pragma unroll
            for (int n = 0; n < 2; ++n) {
                int col = wn * 32 + n * 16 + (l & 15);
                bfr[n] = *reinterpret_cast<const bf16x8*>(&sB[buf][SWZ(col * 64 + kb)]);
            }
            __builtin_amdgcn_s_setprio(1);
            #pragma unroll
            for (int m = 0; m < 2; ++m)
                #pragma unroll
                for (int n = 0; n < 2; ++n)
                    acc[m][n] = __builtin_amdgcn_mfma_f32_16x16x32_bf16(
                        af[m], bfr[n], acc[m][n], 0, 0, 0);
            __builtin_amdgcn_s_setprio(0);
        }
    };

    gll_B(0, 0);
    load_A(0, aX0, aX1);
    load_A(1, aY0, aY1);
    asm volatile("s_waitcnt vmcnt(2)" ::: "memory");
    __builtin_amdgcn_sched_barrier(0);
    write_A(0, aX0, aX1);
    asm volatile("s_waitcnt lgkmcnt(0)" ::: "memory");
    __builtin_amdgcn_s_barrier();
    __builtin_amdgcn_sched_barrier(0);

    const int nk = K >> 6;   // 8
    for (int p = 0; p + 2 < nk; p += 2) {
        gll_B(p + 1, 1);
        load_A(p + 2, aX0, aX1);
        compute(0);
        asm volatile("s_waitcnt vmcnt(4)" ::: "memory");
        __builtin_amdgcn_sched_barrier(0);
        write_A(1, aY0, aY1);
        asm volatile("s_waitcnt vmcnt(2) lgkmcnt(0)" ::: "memory");
        __builtin_amdgcn_s_barrier();
        __builtin_amdgcn_sched_barrier(0);

        gll_B(p + 2, 0);
        load_A(p + 3, aY0, aY1);
        compute(1);
        asm volatile("s_waitcnt vmcnt(4)" ::: "memory");
        __builtin_amdgcn_sched_barrier(0);
        write_A(0, aX0, aX1);
        asm volatile("s_waitcnt vmcnt(2) lgkmcnt(0)" ::: "memory");
        __builtin_amdgcn_s_barrier();
        __builtin_amdgcn_sched_barrier(0);
    }

    gll_B(nk - 1, 1);
    compute(0);
    asm volatile("s_waitcnt vmcnt(2)" ::: "memory");
    __builtin_amdgcn_sched_barrier(0);
    write_A(1, aY0, aY1);
    asm volatile("s_waitcnt vmcnt(0) lgkmcnt(0)" ::: "memory");
    __builtin_amdgcn_s_barrier();
    __builtin_amdgcn_sched_barrier(0);
    compute(1);

    const int jrow = (l >> 4) * 4;
    #pragma unroll
    for (int m = 0; m < 2; ++m) {
        const long row = m0 + wm * 32 + m * 16 + jrow;
        #pragma unroll
        for (int n = 0; n < 2; ++n) {
            const long col = n0 + wn * 32 + n * 16 + (l & 15);
            f32x4 v = acc[m][n];
            if constexpr (EPI == 0) {
                u16x4 o;
                #pragma unroll
                for (int j = 0; j < 4; ++j)
                    o[j] = f2bf(v[j] + epi[(row + j) * lde + col]);
                // Tbt: 256-wide tiles; tile = (col>>8)*128 + (row>>6)
                int tile = ((int)col >> 8) * 128 + ((int)row >> 6);
                int idx = ((int)col & 255) * 64 + ((int)row & 63);
                *reinterpret_cast<u16x4*>(
                    &((unsigned short*)Dptr)[(size_t)tile * 16384 + SWZ(idx)]) = o;
            } else {
                float b = bias[col];
                #pragma unroll
                for (int j = 0; j < 4; ++j)
                    ((float*)Dptr)[(row + j) * ldd + col] = v[j] + b;
            }
        }
    }
}

// ---------------- big GEMM: out += adj @ T ; BM=256,BN=256,BK=64, split-K x4
__global__ __launch_bounds__(512, 2)
void gemm_big(const float* __restrict__ A,            // adj 8192x8192
              const unsigned short* __restrict__ Bt,  // Tbt [2][128][16384]
              float* __restrict__ Out) {              // 8192x512 (pre-filled)
    __shared__ unsigned short sA[2][256 * 64];   // 2 x 32 KB
    __shared__ unsigned short sB[2][256 * 64];   // 2 x 32 KB

    const int t = threadIdx.x;
    const int l = t & 63;
    const int w = t >> 6;
    const int wm = w & 3;        // 4 m-waves (64 rows each)
    const int wn = w >> 2;       // 2 n-waves (128 cols each)

    const int lin = blockIdx.x;          // 256 blocks
    const int combo = lin & 7;           // == hw XCD (round-robin heuristic)
    const int nt = combo & 1;            // N half
    const int kq = combo >> 1;           // K quarter
    const int mt = lin >> 3;             // 0..31

    const long m0 = (long)mt * 256;
    const long k0 = (long)kq * 2048;
    const int n0 = nt * 256;
    const int ktbase = nt * 128 + kq * 32;
    constexpr int P = 32;                // phases of BK=64

    f32x4 acc[4][8];
    #pragma unroll
    for (int mi = 0; mi < 4; ++mi)
        #pragma unroll
        for (int ni = 0; ni < 8; ++ni)
            acc[mi][ni] = {0.f, 0.f, 0.f, 0.f};

    f32x4 avX[8], avY[8];    // two named A reg stages (rule #20)

    auto gll_B = [&](int ph, int buf) {
        const unsigned short* src = Bt + ((size_t)(ktbase + ph)) * 16384 + t * 8;
        #pragma unroll
        for (int r = 0; r < 4; ++r)
            __builtin_amdgcn_global_load_lds(
                (const __attribute__((address_space(1))) void*)(src + r * 4096),
                (__attribute__((address_space(3))) void*)&sB[buf][r * 4096 + w * 512],
                16, 0, 0);
    };

    auto load_A = [&](int ph, f32x4* av) {
        const float* base = A + m0 * 8192 + k0 + (long)ph * 64;
        #pragma unroll
        for (int j = 0; j < 8; ++j) {
            int chunk = j * 512 + t;
            int row = chunk >> 4;
            int kc = (chunk & 15) << 2;
            const float* p = base + (long)row * 8192 + kc;
            asm volatile("global_load_dwordx4 %0, %1, off"
                         : "=&v"(av[j]) : "v"(p) : "memory");
        }
    };

    auto write_A = [&](int buf, const f32x4* av) {
        #pragma unroll
        for (int j = 0; j < 8; ++j) {
            int chunk = j * 512 + t;
            int row = chunk >> 4;
            int kc = (chunk & 15) << 2;
            int idx = row * 64 + kc;
            u16x4 wv = {f2bf(av[j][0]), f2bf(av[j][1]), f2bf(av[j][2]), f2bf(av[j][3])};
            *reinterpret_cast<u16x4*>(&sA[buf][SWZ(idx)]) = wv;
        }
    };

    auto compute = [&](int buf) {
        #pragma unroll
        for (int kk = 0; kk < 2; ++kk) {
            const int kb = kk * 32 + ((l >> 4) << 3);
            bf16x8 af[4], bf[8];
            #pragma unroll
            for (int mi = 0; mi < 4; ++mi) {
                int row = wm * 64 + mi * 16 + (l & 15);
                af[mi] = *reinterpret_cast<const bf16x8*>(&sA[buf][SWZ(row * 64 + kb)]);
            }
            #pragma unroll
            for (int ni = 0; ni < 8; ++ni) {
                int col = wn * 128 + ni * 16 + (l & 15);
                bf[ni] = *reinterpret_cast<const bf16x8*>(&sB[buf][SWZ(col * 64 + kb)]);
            }
            __builtin_amdgcn_s_setprio(1);
            #pragma unroll
            for (int mi = 0; mi < 4; ++mi)
                #pragma unroll
                for (int ni = 0; ni < 8; ++ni)
                    acc[mi][ni] = __builtin_amdgcn_mfma_f32_16x16x32_bf16(
                        af[mi], bf[ni], acc[mi][ni], 0, 0, 0);
            __builtin_amdgcn_s_setprio(0);
        }
    };

    // prologue: ldsA[0]=A(0), ldsB[0]=B(0), avX=A(1) in flight
    gll_B(0, 0);
    load_A(0, avX);
    asm volatile("s_waitcnt vmcnt(0)" ::: "memory");
    __builtin_amdgcn_sched_barrier(0);
    write_A(0, avX);
    load_A(1, avX);
    asm volatile("s_waitcnt lgkmcnt(0)" ::: "memory");
    __builtin_amdgcn_s_barrier();
    __builtin_amdgcn_sched_barrier(0);

    // steady state: entering even p, avX = A(p+1) in flight.
    // clamped tail loads keep vmcnt counts uniform (stray data never read).
    for (int p = 0; p < P; p += 2) {
        gll_B(p + 1 < P ? p + 1 : P - 1, (p + 1) & 1);
        load_A(p + 2 < P ? p + 2 : P - 1, avY);
        asm volatile("s_waitcnt vmcnt(12)" ::: "memory");  // A(p+1) landed
        __builtin_amdgcn_sched_barrier(0);
        write_A((p + 1) & 1, avX);
        compute(p & 1);
        asm volatile("s_waitcnt vmcnt(8) lgkmcnt(0)" ::: "memory"); // B(p+1) in
        __builtin_amdgcn_s_barrier();
        __builtin_amdgcn_sched_barrier(0);

        int q = p + 1;
        gll_B(q + 1 < P ? q + 1 : P - 1, (q + 1) & 1);
        load_A(q + 2 < P ? q + 2 : P - 1, avX);
        asm volatile("s_waitcnt vmcnt(12)" ::: "memory");
        __builtin_amdgcn_sched_barrier(0);
        write_A((q + 1) & 1, avY);
        compute(q & 1);
        asm volatile("s_waitcnt vmcnt(8) lgkmcnt(0)" ::: "memory");
        __builtin_amdgcn_s_barrier();
        __builtin_amdgcn_sched_barrier(0);
    }

    // epilogue: atomic accumulate into pre-filled Out
    #pragma unroll
    for (int mi = 0; mi < 4; ++mi) {
        const long row0 = m0 + wm * 64 + mi * 16 + ((l >> 4) << 2);
        #pragma unroll
        for (int ni = 0; ni < 8; ++ni) {
            const int col = n0 + wn * 128 + ni * 16 + (l & 15);
            #pragma unroll
            for (int j = 0; j < 4; ++j)
                unsafeAtomicAdd(&Out[(row0 + j) * 512 + col], acc[mi][ni][j]);
        }
    }
}

extern "C" void kernel_launch(void* const* d_in, const int* in_sizes, int n_in,
                              void* d_out, int out_size, void* d_ws, size_t ws_size,
                              hipStream_t stream) {
    const float* input  = (const float*)d_in[0];   // 8192 x 512
    const float* adj    = (const float*)d_in[1];   // 8192 x 8192
    const float* x      = (const float*)d_in[2];   // 8192 x 512
    const float* weight = (const float*)d_in[3];   // 9216 x 512
    const float* bias   = (const float*)d_in[4];   // 512

    const int N = 8192, IN_F = 512, NFEAT = 512, OUT_F = 512;
    float* out = (float*)d_out;

    // workspace (~9.5 MB)
    unsigned short* Tbt = (unsigned short*)d_ws;            // [2][128][16384]
    unsigned short* W1t = Tbt + (size_t)2 * 128 * 16384;    // [4][8][8192]
    unsigned short* W3t = W1t + (size_t)4 * 8 * 8192;       // [4][8][8192]

    transpose_cvt<<<dim3((IN_F * OUT_F) / 256), dim3(256), 0, stream>>>(
        weight, W1t, IN_F, OUT_F, 7);
    transpose_cvt<<<dim3((NFEAT * OUT_F) / 256), dim3(256), 0, stream>>>(
        weight + (size_t)(IN_F + N) * OUT_F, W3t, NFEAT, OUT_F, 7);

    dim3 grid(OUT_F / 128, N / 64);   // (4, 128) = 512 blocks

    // out = x @ W3 + bias   (pre-fill for big-GEMM atomics)
    gemm_small<1><<<grid, 512, 0, stream>>>(
        x, (long)NFEAT, W3t, NFEAT,
        nullptr, 0, bias,
        out, (long)OUT_F);

    // Tbt = (input @ W1 + W2) in 256-wide tiled+swizzled bf16
    gemm_small<0><<<grid, 512, 0, stream>>>(
        input, (long)IN_F, W1t, IN_F,
        weight + (size_t)IN_F * OUT_F, (long)OUT_F, nullptr,
        Tbt, 0);

    // out += adj @ T
    gemm_big<<<dim3(256), dim3(512), 0, stream>>>(adj, Tbt, out);
}

// Round 5
// 182.878 us; speedup vs baseline: 1.3598x; 1.3598x over previous
//
#include <hip/hip_runtime.h>
#include <hip/hip_bf16.h>

typedef __attribute__((ext_vector_type(4))) float f32x4;
typedef __attribute__((ext_vector_type(8))) short bf16x8;
typedef __attribute__((ext_vector_type(4))) unsigned short u16x4;
typedef __attribute__((ext_vector_type(8))) unsigned short u16x8;

__device__ __forceinline__ unsigned short f2bf(float f) {
    unsigned int u = __builtin_bit_cast(unsigned int, f);
    u += 0x7fffu + ((u >> 16) & 1u);   // RNE; inputs finite
    return (unsigned short)(u >> 16);
}

// swizzle in ushort units: rows are 64 ushorts (128 B); XOR bits 3..5 with row&7
#define SWZ(i) ((i) ^ ((((i) >> 6) & 7) << 3))

// ---------------- transpose+convert: W^T into tiled+swizzled bf16 ----------
__global__ void transpose_cvt(const float* __restrict__ src,
                              unsigned short* __restrict__ dst,
                              int rows, int cols, int ltw) {
    int idx = blockIdx.x * 256 + threadIdx.x;     // idx = n*rows + k
    int n = idx / rows;
    int k = idx - n * rows;
    unsigned short v = f2bf(src[(size_t)k * cols + n]);
    int tw = 1 << ltw;
    int tile = (n >> ltw) * (rows >> 6) + (k >> 6);
    dst[(size_t)tile * (tw * 64) + SWZ((n & (tw - 1)) * 64 + (k & 63))] = v;
}

// ---------------- small GEMM (K=512): BM=64, BN=128 -----------------------
// EPI 0: D = Tbt (256-wide tiled+swizzled bf16) = acc + epi  [T = input@W1+W2]
// EPI 1: D(f32) = acc + bias[col]  -> writes OUT directly    [out = x@W3 + b]
template<int EPI>
__global__ __launch_bounds__(512, 4)
void gemm_small(const float* __restrict__ A, long lda,
                const unsigned short* __restrict__ Bt,
                int K,
                const float* __restrict__ epi, long lde,
                const float* __restrict__ bias,
                void* __restrict__ Dptr, long ldd) {
    __shared__ unsigned short sA[2][64 * 64];
    __shared__ unsigned short sB[2][128 * 64];

    const int t = threadIdx.x;
    const int l = t & 63;
    const int w = t >> 6;
    const int wm = w >> 2;              // 0..1
    const int wn = w & 3;               // 0..3

    int mt, nt;
    {
        int lin = blockIdx.y * gridDim.x + blockIdx.x;   // gridDim.y % 8 == 0
        int xcd = lin & 7;
        int slot = lin >> 3;
        int ppx = gridDim.y >> 3;
        mt = xcd * ppx + slot / gridDim.x;
        nt = slot % gridDim.x;
    }
    const long m0 = (long)mt * 64;
    const long n0 = (long)nt * 128;
    const int KT = K >> 6;
    const unsigned short* Bblk = Bt + (size_t)nt * KT * 8192;

    f32x4 acc[2][2];
    #pragma unroll
    for (int m = 0; m < 2; ++m)
        #pragma unroll
        for (int n = 0; n < 2; ++n)
            acc[m][n] = {0.f, 0.f, 0.f, 0.f};

    f32x4 aX0, aX1, aY0, aY1;

    auto gll_B = [&](int kt, int buf) {
        const unsigned short* src = Bblk + (size_t)kt * 8192 + t * 8;
        #pragma unroll
        for (int r = 0; r < 2; ++r)
            __builtin_amdgcn_global_load_lds(
                (const __attribute__((address_space(1))) void*)(src + r * 4096),
                (__attribute__((address_space(3))) void*)&sB[buf][r * 4096 + w * 512],
                16, 0, 0);
    };

    auto load_A = [&](int kt, f32x4& a0, f32x4& a1) {
        const float* p0 = &A[(m0 + (t >> 4)) * lda + (long)kt * 64 + ((t & 15) << 2)];
        const float* p1 = p0 + 32 * lda;
        asm volatile("global_load_dwordx4 %0, %2, off\n\t"
                     "global_load_dwordx4 %1, %3, off"
                     : "=&v"(a0), "=&v"(a1)
                     : "v"(p0), "v"(p1)
                     : "memory");
    };

    auto write_A = [&](int buf, const f32x4& a0, const f32x4& a1) {
        int e0 = t * 4;
        u16x4 w0 = {f2bf(a0[0]), f2bf(a0[1]), f2bf(a0[2]), f2bf(a0[3])};
        *reinterpret_cast<u16x4*>(&sA[buf][SWZ(e0)]) = w0;
        int e1 = 2048 + t * 4;
        u16x4 w1 = {f2bf(a1[0]), f2bf(a1[1]), f2bf(a1[2]), f2bf(a1[3])};
        *reinterpret_cast<u16x4*>(&sA[buf][SWZ(e1)]) = w1;
    };

    auto compute = [&](int buf) {
        #pragma unroll
        for (int kk = 0; kk < 2; ++kk) {
            bf16x8 af[2], bfr[2];
            const int kb = kk * 32 + ((l >> 4) << 3);
            #pragma unroll
            for (int m = 0; m < 2; ++m) {
                int row = wm * 32 + m * 16 + (l & 15);
                af[m] = *reinterpret_cast<const bf16x8*>(&sA[buf][SWZ(row * 64 + kb)]);
            }
            #pragma unroll
            for (int n = 0; n < 2; ++n) {
                int col = wn * 32 + n * 16 + (l & 15);
                bfr[n] = *reinterpret_cast<const bf16x8*>(&sB[buf][SWZ(col * 64 + kb)]);
            }
            __builtin_amdgcn_s_setprio(1);
            #pragma unroll
            for (int m = 0; m < 2; ++m)
                #pragma unroll
                for (int n = 0; n < 2; ++n)
                    acc[m][n] = __builtin_amdgcn_mfma_f32_16x16x32_bf16(
                        af[m], bfr[n], acc[m][n], 0, 0, 0);
            __builtin_amdgcn_s_setprio(0);
        }
    };

    gll_B(0, 0);
    load_A(0, aX0, aX1);
    load_A(1, aY0, aY1);
    asm volatile("s_waitcnt vmcnt(2)" ::: "memory");
    __builtin_amdgcn_sched_barrier(0);
    write_A(0, aX0, aX1);
    asm volatile("s_waitcnt lgkmcnt(0)" ::: "memory");
    __builtin_amdgcn_s_barrier();
    __builtin_amdgcn_sched_barrier(0);

    const int nk = K >> 6;   // 8
    for (int p = 0; p + 2 < nk; p += 2) {
        gll_B(p + 1, 1);
        load_A(p + 2, aX0, aX1);
        compute(0);
        asm volatile("s_waitcnt vmcnt(4)" ::: "memory");
        __builtin_amdgcn_sched_barrier(0);
        write_A(1, aY0, aY1);
        asm volatile("s_waitcnt vmcnt(2) lgkmcnt(0)" ::: "memory");
        __builtin_amdgcn_s_barrier();
        __builtin_amdgcn_sched_barrier(0);

        gll_B(p + 2, 0);
        load_A(p + 3, aY0, aY1);
        compute(1);
        asm volatile("s_waitcnt vmcnt(4)" ::: "memory");
        __builtin_amdgcn_sched_barrier(0);
        write_A(0, aX0, aX1);
        asm volatile("s_waitcnt vmcnt(2) lgkmcnt(0)" ::: "memory");
        __builtin_amdgcn_s_barrier();
        __builtin_amdgcn_sched_barrier(0);
    }

    gll_B(nk - 1, 1);
    compute(0);
    asm volatile("s_waitcnt vmcnt(2)" ::: "memory");
    __builtin_amdgcn_sched_barrier(0);
    write_A(1, aY0, aY1);
    asm volatile("s_waitcnt vmcnt(0) lgkmcnt(0)" ::: "memory");
    __builtin_amdgcn_s_barrier();
    __builtin_amdgcn_sched_barrier(0);
    compute(1);

    const int jrow = (l >> 4) * 4;
    #pragma unroll
    for (int m = 0; m < 2; ++m) {
        const long row = m0 + wm * 32 + m * 16 + jrow;
        #pragma unroll
        for (int n = 0; n < 2; ++n) {
            const long col = n0 + wn * 32 + n * 16 + (l & 15);
            f32x4 v = acc[m][n];
            if constexpr (EPI == 0) {
                u16x4 o;
                #pragma unroll
                for (int j = 0; j < 4; ++j)
                    o[j] = f2bf(v[j] + epi[(row + j) * lde + col]);
                int tile = ((int)col >> 8) * 128 + ((int)row >> 6);
                int idx = ((int)col & 255) * 64 + ((int)row & 63);
                *reinterpret_cast<u16x4*>(
                    &((unsigned short*)Dptr)[(size_t)tile * 16384 + SWZ(idx)]) = o;
            } else {
                float b = bias[col];
                #pragma unroll
                for (int j = 0; j < 4; ++j)
                    ((float*)Dptr)[(row + j) * ldd + col] = v[j] + b;
            }
        }
    }
}

// ---------------- big GEMM: out += adj @ T ; BM=256,BN=256,BK=64, split-K x4
// Block map: XCD slot = lin&7 -> (kq, mhalf); both nt of each (mt,kq) pair are
// co-resident on one XCD so the shared 2 MB adj slab is HBM-fetched once and
// the partner reads it from L2. Per-XCD B working set = 2 MB (L2-resident).
__global__ __launch_bounds__(512, 2)
void gemm_big(const float* __restrict__ A,            // adj 8192x8192
              const unsigned short* __restrict__ Bt,  // Tbt [2][128][16384]
              float* __restrict__ Out) {              // 8192x512 (pre-filled)
    __shared__ unsigned short sA[2][256 * 64];   // 2 x 32 KB
    __shared__ unsigned short sB[2][256 * 64];   // 2 x 32 KB

    const int t = threadIdx.x;
    const int l = t & 63;
    const int w = t >> 6;
    const int wm = w & 3;        // 4 m-waves (64 rows each)
    const int wn = w >> 2;       // 2 n-waves (128 cols each)

    const int lin = blockIdx.x;          // 256 blocks
    const int slot = lin & 7;            // == hw XCD (round-robin heuristic)
    const int kq = slot & 3;             // K quarter
    const int mhalf = slot >> 1 >> 1;    // slot>>2: M half
    const int idx = lin >> 3;            // 0..31
    const int nt = idx & 1;              // N half  (nt-pair adjacent -> co-XCD)
    const int mt = mhalf * 16 + (idx >> 1);

    const long m0 = (long)mt * 256;
    const long k0 = (long)kq * 2048;
    const int n0 = nt * 256;
    const int ktbase = nt * 128 + kq * 32;
    constexpr int P = 32;                // phases of BK=64

    f32x4 acc[4][8];
    #pragma unroll
    for (int mi = 0; mi < 4; ++mi)
        #pragma unroll
        for (int ni = 0; ni < 8; ++ni)
            acc[mi][ni] = {0.f, 0.f, 0.f, 0.f};

    f32x4 avH[8];    // single named A reg stage

    auto gll_B = [&](int ph, int buf) {
        const unsigned short* src = Bt + ((size_t)(ktbase + ph)) * 16384 + t * 8;
        #pragma unroll
        for (int r = 0; r < 4; ++r)
            __builtin_amdgcn_global_load_lds(
                (const __attribute__((address_space(1))) void*)(src + r * 4096),
                (__attribute__((address_space(3))) void*)&sB[buf][r * 4096 + w * 512],
                16, 0, 0);
    };

    auto load_A = [&](int ph) {
        const float* base = A + m0 * 8192 + k0 + (long)ph * 64;
        #pragma unroll
        for (int j = 0; j < 8; ++j) {
            int chunk = j * 512 + t;
            int row = chunk >> 4;
            int kc = (chunk & 15) << 2;
            const float* p = base + (long)row * 8192 + kc;
            asm volatile("global_load_dwordx4 %0, %1, off"
                         : "=&v"(avH[j]) : "v"(p) : "memory");
        }
    };

    auto write_A = [&](int buf) {
        #pragma unroll
        for (int j = 0; j < 8; ++j) {
            int chunk = j * 512 + t;
            int row = chunk >> 4;
            int kc = (chunk & 15) << 2;
            int idx2 = row * 64 + kc;
            u16x4 wv = {f2bf(avH[j][0]), f2bf(avH[j][1]), f2bf(avH[j][2]), f2bf(avH[j][3])};
            *reinterpret_cast<u16x4*>(&sA[buf][SWZ(idx2)]) = wv;
        }
    };

    auto compute = [&](int buf) {
        #pragma unroll
        for (int kk = 0; kk < 2; ++kk) {
            const int kb = kk * 32 + ((l >> 4) << 3);
            bf16x8 af[4], bf[8];
            #pragma unroll
            for (int mi = 0; mi < 4; ++mi) {
                int row = wm * 64 + mi * 16 + (l & 15);
                af[mi] = *reinterpret_cast<const bf16x8*>(&sA[buf][SWZ(row * 64 + kb)]);
            }
            #pragma unroll
            for (int ni = 0; ni < 8; ++ni) {
                int col = wn * 128 + ni * 16 + (l & 15);
                bf[ni] = *reinterpret_cast<const bf16x8*>(&sB[buf][SWZ(col * 64 + kb)]);
            }
            __builtin_amdgcn_s_setprio(1);
            #pragma unroll
            for (int mi = 0; mi < 4; ++mi)
                #pragma unroll
                for (int ni = 0; ni < 8; ++ni)
                    acc[mi][ni] = __builtin_amdgcn_mfma_f32_16x16x32_bf16(
                        af[mi], bf[ni], acc[mi][ni], 0, 0, 0);
            __builtin_amdgcn_s_setprio(0);
        }
    };

    // ---- prologue: A(0) regs, B(0) gll -> buf0; then A(1) in flight ----
    load_A(0);                                         // 8 outstanding
    gll_B(0, 0);                                       // 12
    asm volatile("s_waitcnt vmcnt(4)" ::: "memory");   // A(0) landed
    __builtin_amdgcn_sched_barrier(0);
    write_A(0);
    load_A(1);                                         // 4 + 8 = 12
    asm volatile("s_waitcnt vmcnt(8) lgkmcnt(0)" ::: "memory");  // B(0) landed
    __builtin_amdgcn_s_barrier();
    __builtin_amdgcn_sched_barrier(0);

    // steady: entering phase p, LDS[p&1] valid, avH = A(p+1) in flight (8)
    for (int p = 0; p < P - 2; ++p) {
        gll_B(p + 1, (p + 1) & 1);                     // 12 outstanding
        asm volatile("s_waitcnt vmcnt(4)" ::: "memory");   // A(p+1) landed
        __builtin_amdgcn_sched_barrier(0);
        write_A((p + 1) & 1);
        load_A(p + 2);                                 // 4 + 8 = 12
        compute(p & 1);
        asm volatile("s_waitcnt vmcnt(8) lgkmcnt(0)" ::: "memory"); // B(p+1) in
        __builtin_amdgcn_s_barrier();
        __builtin_amdgcn_sched_barrier(0);
    }

    // phase P-2: avH = A(P-1) in flight; no further A loads
    gll_B(P - 1, (P - 1) & 1);
    asm volatile("s_waitcnt vmcnt(4)" ::: "memory");   // A(P-1) landed
    __builtin_amdgcn_sched_barrier(0);
    write_A((P - 1) & 1);
    compute((P - 2) & 1);
    asm volatile("s_waitcnt vmcnt(0) lgkmcnt(0)" ::: "memory");
    __builtin_amdgcn_s_barrier();
    __builtin_amdgcn_sched_barrier(0);

    // phase P-1
    compute((P - 1) & 1);

    // epilogue: atomic accumulate into pre-filled Out
    #pragma unroll
    for (int mi = 0; mi < 4; ++mi) {
        const long row0 = m0 + wm * 64 + mi * 16 + ((l >> 4) << 2);
        #pragma unroll
        for (int ni = 0; ni < 8; ++ni) {
            const int col = n0 + wn * 128 + ni * 16 + (l & 15);
            #pragma unroll
            for (int j = 0; j < 4; ++j)
                unsafeAtomicAdd(&Out[(row0 + j) * 512 + col], acc[mi][ni][j]);
        }
    }
}

extern "C" void kernel_launch(void* const* d_in, const int* in_sizes, int n_in,
                              void* d_out, int out_size, void* d_ws, size_t ws_size,
                              hipStream_t stream) {
    const float* input  = (const float*)d_in[0];   // 8192 x 512
    const float* adj    = (const float*)d_in[1];   // 8192 x 8192
    const float* x      = (const float*)d_in[2];   // 8192 x 512
    const float* weight = (const float*)d_in[3];   // 9216 x 512
    const float* bias   = (const float*)d_in[4];   // 512

    const int N = 8192, IN_F = 512, NFEAT = 512, OUT_F = 512;
    float* out = (float*)d_out;

    // workspace (~9.5 MB)
    unsigned short* Tbt = (unsigned short*)d_ws;            // [2][128][16384]
    unsigned short* W1t = Tbt + (size_t)2 * 128 * 16384;    // [4][8][8192]
    unsigned short* W3t = W1t + (size_t)4 * 8 * 8192;       // [4][8][8192]

    transpose_cvt<<<dim3((IN_F * OUT_F) / 256), dim3(256), 0, stream>>>(
        weight, W1t, IN_F, OUT_F, 7);
    transpose_cvt<<<dim3((NFEAT * OUT_F) / 256), dim3(256), 0, stream>>>(
        weight + (size_t)(IN_F + N) * OUT_F, W3t, NFEAT, OUT_F, 7);

    dim3 grid(OUT_F / 128, N / 64);   // (4, 128) = 512 blocks

    // out = x @ W3 + bias   (pre-fill for big-GEMM atomics)
    gemm_small<1><<<grid, 512, 0, stream>>>(
        x, (long)NFEAT, W3t, NFEAT,
        nullptr, 0, bias,
        out, (long)OUT_F);

    // Tbt = (input @ W1 + W2) in 256-wide tiled+swizzled bf16
    gemm_small<0><<<grid, 512, 0, stream>>>(
        input, (long)IN_F, W1t, IN_F,
        weight + (size_t)IN_F * OUT_F, (long)OUT_F, nullptr,
        Tbt, 0);

    // out += adj @ T
    gemm_big<<<dim3(256), dim3(512), 0, stream>>>(adj, Tbt, out);
}